// Round 7
// baseline (239.337 us; speedup 1.0000x reference)
//
#include <hip/hip_runtime.h>
#include <cstdint>
#include <cstddef>

#define NB 2048
#define NT 512
#define ND 64
#define NR 50
#define NKK 16
#define REVP 68   // review row stride (floats)

typedef __attribute__((ext_vector_type(8))) short bf16x8;
typedef __attribute__((ext_vector_type(4))) float f32x4;

__device__ inline unsigned short f2bf_rne(float x) {
    unsigned int u = __float_as_uint(x);
    u += 0x7fffu + ((u >> 16) & 1u);
    return (unsigned short)(u >> 16);
}

// split 8 f32 -> hi (truncate) / lo (RNE of remainder), packed as bf16x8
__device__ inline void cvt8_fast(float4 v0, float4 v1, bf16x8& ah, bf16x8& al) {
    float f[8] = {v0.x, v0.y, v0.z, v0.w, v1.x, v1.y, v1.z, v1.w};
    union { unsigned int u[4]; bf16x8 v; } H, L;
#pragma unroll
    for (int p = 0; p < 4; ++p) {
        unsigned int u0 = __float_as_uint(f[2*p]);
        unsigned int u1 = __float_as_uint(f[2*p+1]);
        H.u[p] = (u0 >> 16) | (u1 & 0xffff0000u);
        float r0 = f[2*p]   - __uint_as_float(u0 & 0xffff0000u);
        float r1 = f[2*p+1] - __uint_as_float(u1 & 0xffff0000u);
        unsigned int lp;
        asm("v_cvt_pk_bf16_f32 %0, %1, %2" : "=v"(lp) : "v"(r0), "v"(r1));
        L.u[p] = lp;
    }
    ah = H.v; al = L.v;
}

// ---------------------------------------------------------------------------
// Pack topic_w into main-GEMM B-frag order (hi/lo) and fc weights into
// epilogue B-frag order (K=128: rows 0-63 = fc_r_w, 64-127 = fc_a_w).
__global__ __launch_bounds__(256) void prep_kernel(
    const float* __restrict__ tw,
    const float* __restrict__ fc_u_w, const float* __restrict__ fc_ru_w,
    const float* __restrict__ fc_i_w, const float* __restrict__ fc_ri_w,
    unsigned short* __restrict__ bhi, unsigned short* __restrict__ blo,
    unsigned short* __restrict__ fuhi, unsigned short* __restrict__ fulo,
    unsigned short* __restrict__ fihi, unsigned short* __restrict__ filo)
{
    int i = blockIdx.x * 256 + threadIdx.x;          // 192*256 = 49152
    if (i < 32768) {
        int j  = i & 7;
        int l  = (i >> 3) & 63;
        int n  = (i >> 9) & 3;
        int kk = i >> 11;                            // 0..15
        int t = kk * 32 + ((l >> 4) << 3) + j;
        int d = n * 16 + (l & 15);
        float x = tw[t * ND + d];
        unsigned int u = __float_as_uint(x);
        bhi[i] = (unsigned short)(u >> 16);
        blo[i] = f2bf_rne(x - __uint_as_float(u & 0xffff0000u));
    } else {
        int q = i - 32768;                           // 0..16383
        int br = q >> 13;                            // 0 user, 1 item
        int e = q & 8191;
        int j  = e & 7;
        int l  = (e >> 3) & 63;
        int n  = (e >> 9) & 3;
        int kk = e >> 11;                            // 0..3
        int k = kk * 32 + ((l >> 4) << 3) + j;       // 0..127
        int col = n * 16 + (l & 15);
        const float* W = (k < 64) ? (br ? fc_ri_w : fc_ru_w)
                                  : (br ? fc_i_w  : fc_u_w);
        float x = W[(k & 63) * ND + col];
        unsigned int u = __float_as_uint(x);
        unsigned short hi = (unsigned short)(u >> 16);
        unsigned short lo = f2bf_rne(x - __uint_as_float(u & 0xffff0000u));
        if (br) { fihi[e] = hi; filo[e] = lo; }
        else    { fuhi[e] = hi; fulo[e] = lo; }
    }
}

// ---------------------------------------------------------------------------
__global__ __launch_bounds__(256) void colsum_kernel(const float* __restrict__ tw,
                                                     float* __restrict__ colsum) {
    __shared__ float part[4][ND];
    int d = threadIdx.x & 63, p = threadIdx.x >> 6;
    float s = 0.f;
    for (int t = p; t < NT; t += 4) s += tw[t * ND + d];
    part[p][d] = s;
    __syncthreads();
    if (threadIdx.x < ND)
        colsum[d] = part[0][d] + part[1][d] + part[2][d] + part[3][d];
}

// ---------------------------------------------------------------------------
// One block per (branch, batch element). 4 waves, zero barriers in K-loop.
// FULLY-UNROLLED register pipeline with sched_barrier(0) pinning:
//   A depth-2 prefetch, B-hi/B-lo depth-1 prefetch. Loads cannot be sunk
//   past the barrier -> they genuinely stay in flight (VGPR will show it).
__global__ __launch_bounds__(256, 3) void branch_kernel(
    const int* __restrict__ user, const int* __restrict__ item,
    const float* __restrict__ user_r_topic, const float* __restrict__ item_r_topic,
    const float* __restrict__ user_embed_w, const float* __restrict__ item_embed_w,
    const float* __restrict__ user_att_w, const float* __restrict__ item_att_w,
    const unsigned short* __restrict__ bhi, const unsigned short* __restrict__ blo,
    const unsigned short* __restrict__ fuhi, const unsigned short* __restrict__ fulo,
    const unsigned short* __restrict__ fihi, const unsigned short* __restrict__ filo,
    const float* __restrict__ fc_u_b, const float* __restrict__ fc_ru_b,
    const float* __restrict__ fc_i_b, const float* __restrict__ fc_ri_b,
    const float* __restrict__ h_u_w, const float* __restrict__ h_u_b,
    const float* __restrict__ h_i_w, const float* __restrict__ h_i_b,
    const float* __restrict__ colsum,
    float* __restrict__ u_vec, float* __restrict__ i_vec)
{
    const int bb = blockIdx.x;
    const int branch = bb >> 11;          // 0 = user, 1 = item
    const int b = bb & (NB - 1);

    const int*   ids     = branch ? item           : user;
    const float* r_topic = branch ? item_r_topic   : user_r_topic;
    const float* emb_w   = branch ? item_embed_w   : user_embed_w;
    const float* att_w   = branch ? item_att_w     : user_att_w;
    const unsigned short* fhi = branch ? fihi : fuhi;
    const unsigned short* flo = branch ? filo : fulo;
    const float* fc_a_b  = branch ? fc_i_b         : fc_u_b;
    const float* fc_r_b  = branch ? fc_ri_b        : fc_ru_b;
    const float* h_w     = branch ? h_i_w          : h_u_w;
    const float* h_b     = branch ? h_i_b          : h_u_b;
    float*       out_vec = branch ? i_vec          : u_vec;

    __shared__ float rev[NR][REVP];       // 13.6 KB
    __shared__ float lds_logit[NR + 2];

    const int tid = threadIdx.x, wave = tid >> 6, lane = tid & 63;
    const int g = lane >> 4, c16 = lane & 15;
    const int id = ids[b];

    const int rowm = wave * 16 + c16;
    const int rowc = rowm < NR ? rowm : NR - 1;
    const float* arow = r_topic + (size_t)b * NR * NT + (size_t)rowc * NT + g * 8;

    f32x4 acc[4];
#pragma unroll
    for (int n = 0; n < 4; ++n) acc[n] = (f32x4){0.f, 0.f, 0.f, 0.f};

    // Full-unroll SSA arrays (all indices static after unroll)
    float4 Aa[NKK], Ab[NKK];
    bf16x8 BH[NKK][4], BL[NKK][4];

    // ---- prologue: A steps 0,1 ; B step 0 ----
    Aa[0] = *reinterpret_cast<const float4*>(arow);
    Ab[0] = *reinterpret_cast<const float4*>(arow + 4);
    Aa[1] = *reinterpret_cast<const float4*>(arow + 32);
    Ab[1] = *reinterpret_cast<const float4*>(arow + 36);
#pragma unroll
    for (int n = 0; n < 4; ++n) {
        BH[0][n] = *(reinterpret_cast<const bf16x8*>(bhi) + n * 64 + lane);
        BL[0][n] = *(reinterpret_cast<const bf16x8*>(blo) + n * 64 + lane);
    }
    __builtin_amdgcn_sched_barrier(0);

#pragma unroll
    for (int kk = 0; kk < NKK; ++kk) {
        // ---- issue region: loads for future steps ----
        if (kk + 2 < NKK) {
            Aa[kk + 2] = *reinterpret_cast<const float4*>(arow + (kk + 2) * 32);
            Ab[kk + 2] = *reinterpret_cast<const float4*>(arow + (kk + 2) * 32 + 4);
        }
        if (kk + 1 < NKK) {
#pragma unroll
            for (int n = 0; n < 4; ++n) {
                BH[kk + 1][n] = *(reinterpret_cast<const bf16x8*>(bhi + (size_t)(kk + 1) * 2048) + n * 64 + lane);
                BL[kk + 1][n] = *(reinterpret_cast<const bf16x8*>(blo + (size_t)(kk + 1) * 2048) + n * 64 + lane);
            }
        }
        __builtin_amdgcn_sched_barrier(0);   // loads may not sink below here

        // ---- compute region: step kk ----
        bf16x8 ah, al;
        cvt8_fast(Aa[kk], Ab[kk], ah, al);
#pragma unroll
        for (int n = 0; n < 4; ++n)
            acc[n] = __builtin_amdgcn_mfma_f32_16x16x32_bf16(ah, BH[kk][n], acc[n], 0, 0, 0);
#pragma unroll
        for (int n = 0; n < 4; ++n)
            acc[n] = __builtin_amdgcn_mfma_f32_16x16x32_bf16(al, BH[kk][n], acc[n], 0, 0, 0);
#pragma unroll
        for (int n = 0; n < 4; ++n)
            acc[n] = __builtin_amdgcn_mfma_f32_16x16x32_bf16(ah, BL[kk][n], acc[n], 0, 0, 0);
    }

    // C layout: lane holds rows g*4+r4 (within wave tile), col n*16+c16
#pragma unroll
    for (int n = 0; n < 4; ++n)
#pragma unroll
        for (int r4 = 0; r4 < 4; ++r4) {
            int r = wave * 16 + g * 4 + r4;
            if (r < NR) rev[r][n * 16 + c16] = acc[n][r4];
        }
    // no barrier: epilogue reads only this wave's own rows

    // ---- epilogue s-matmul: s[50x64] = review@fcR + att@fcA (K=128) ----
    f32x4 s4[4];
#pragma unroll
    for (int n = 0; n < 4; ++n) s4[n] = (f32x4){0.f, 0.f, 0.f, 0.f};

#pragma unroll
    for (int kk2 = 0; kk2 < 4; ++kk2) {
        bf16x8 bh[4], bl[4];
#pragma unroll
        for (int n = 0; n < 4; ++n) {
            bh[n] = *(reinterpret_cast<const bf16x8*>(fhi + (size_t)(kk2 * 4 + n) * 512) + lane);
            bl[n] = *(reinterpret_cast<const bf16x8*>(flo + (size_t)(kk2 * 4 + n) * 512) + lane);
        }
        bf16x8 ah, al;
        if (kk2 < 2) {
            const float* rp = &rev[rowc][kk2 * 32 + g * 8];
            cvt8_fast(*reinterpret_cast<const float4*>(rp),
                      *reinterpret_cast<const float4*>(rp + 4), ah, al);
        } else {
            const float* ap = att_w + (size_t)id * ND + (kk2 - 2) * 32 + g * 8;
            cvt8_fast(*reinterpret_cast<const float4*>(ap),
                      *reinterpret_cast<const float4*>(ap + 4), ah, al);
        }
#pragma unroll
        for (int n = 0; n < 4; ++n) {
            s4[n] = __builtin_amdgcn_mfma_f32_16x16x32_bf16(ah, bh[n], s4[n], 0, 0, 0);
            s4[n] = __builtin_amdgcn_mfma_f32_16x16x32_bf16(al, bh[n], s4[n], 0, 0, 0);
            s4[n] = __builtin_amdgcn_mfma_f32_16x16x32_bf16(ah, bl[n], s4[n], 0, 0, 0);
        }
    }

    // bias + relu + dot with h_w, then 16-lane reduce -> logits
    const float hb = h_b[0];
    float p0 = 0.f, p1 = 0.f, p2 = 0.f, p3 = 0.f;
#pragma unroll
    for (int n = 0; n < 4; ++n) {
        float hwn = h_w[n * 16 + c16];
        float bs = fc_r_b[n * 16 + c16] + fc_a_b[n * 16 + c16];
        p0 = fmaf(fmaxf(s4[n][0] + bs, 0.f), hwn, p0);
        p1 = fmaf(fmaxf(s4[n][1] + bs, 0.f), hwn, p1);
        p2 = fmaf(fmaxf(s4[n][2] + bs, 0.f), hwn, p2);
        p3 = fmaf(fmaxf(s4[n][3] + bs, 0.f), hwn, p3);
    }
#pragma unroll
    for (int off = 1; off < 16; off <<= 1) {
        p0 += __shfl_xor(p0, off);
        p1 += __shfl_xor(p1, off);
        p2 += __shfl_xor(p2, off);
        p3 += __shfl_xor(p3, off);
    }
    if (c16 == 0) {
        int rb = wave * 16 + g * 4;
        if (rb + 0 < NR) lds_logit[rb + 0] = p0 + hb;
        if (rb + 1 < NR) lds_logit[rb + 1] = p1 + hb;
        if (rb + 2 < NR) lds_logit[rb + 2] = p2 + hb;
        if (rb + 3 < NR) lds_logit[rb + 3] = p3 + hb;
    }
    __syncthreads();   // the ONLY barrier: publish rev rows + logits to wave 0

    // softmax + pooling + colsum scale + emb add (wave 0)
    if (wave == 0) {
        float m = -1e30f;
        for (int r = 0; r < NR; ++r) m = fmaxf(m, lds_logit[r]);
        float sum = 0.f;
        for (int r = 0; r < NR; ++r) sum += __expf(lds_logit[r] - m);
        float inv = 1.f / sum;
        float feat = 0.f;
        for (int r = 0; r < NR; ++r)
            feat = fmaf(__expf(lds_logit[r] - m), rev[r][lane], feat);
        feat *= inv;
        out_vec[(size_t)b * ND + lane] = feat * colsum[lane] + emb_w[(size_t)id * ND + lane];
    }
}

// ---------------------------------------------------------------------------
__global__ __launch_bounds__(64) void final_kernel(
    const float* __restrict__ u_vec, const float* __restrict__ i_vec,
    const float* __restrict__ fc_pre_w, const float* __restrict__ fc_pre_b,
    float* __restrict__ out)
{
    int b = blockIdx.x, lane = threadIdx.x;
    float v = u_vec[(size_t)b * ND + lane] * fc_pre_w[lane]
            + i_vec[(size_t)b * ND + lane] * fc_pre_w[ND + lane];
#pragma unroll
    for (int off = 32; off; off >>= 1) v += __shfl_xor(v, off);
    if (lane == 0) out[b] = fmaxf(v + fc_pre_b[0], 0.f);
}

// ---------------------------------------------------------------------------
extern "C" void kernel_launch(void* const* d_in, const int* in_sizes, int n_in,
                              void* d_out, int out_size, void* d_ws, size_t ws_size,
                              hipStream_t stream) {
    (void)in_sizes; (void)n_in; (void)out_size; (void)ws_size;

    const int*   user         = (const int*)d_in[0];
    const int*   item         = (const int*)d_in[1];
    const float* user_r_topic = (const float*)d_in[2];
    const float* item_r_topic = (const float*)d_in[3];
    const float* user_embed_w = (const float*)d_in[4];
    const float* item_embed_w = (const float*)d_in[5];
    const float* user_att_w   = (const float*)d_in[6];
    const float* item_att_w   = (const float*)d_in[7];
    const float* topic_w      = (const float*)d_in[8];
    const float* fc_u_w       = (const float*)d_in[9];
    const float* fc_u_b       = (const float*)d_in[10];
    const float* fc_ru_w      = (const float*)d_in[11];
    const float* fc_ru_b      = (const float*)d_in[12];
    const float* fc_i_w       = (const float*)d_in[13];
    const float* fc_i_b       = (const float*)d_in[14];
    const float* fc_ri_w      = (const float*)d_in[15];
    const float* fc_ri_b      = (const float*)d_in[16];
    const float* h_u_w        = (const float*)d_in[17];
    const float* h_u_b        = (const float*)d_in[18];
    const float* h_i_w        = (const float*)d_in[19];
    const float* h_i_b        = (const float*)d_in[20];
    const float* fc_pre_w     = (const float*)d_in[21];
    const float* fc_pre_b     = (const float*)d_in[22];

    // workspace layout
    unsigned short* bhi  = (unsigned short*)d_ws;      // 32768
    unsigned short* blo  = bhi + 32768;                // 32768
    unsigned short* fuhi = blo + 32768;                // 8192
    unsigned short* fulo = fuhi + 8192;
    unsigned short* fihi = fulo + 8192;
    unsigned short* filo = fihi + 8192;
    float* colsum = (float*)(filo + 8192);             // 64
    float* u_vec  = colsum + 64;                       // NB*ND
    float* i_vec  = u_vec + NB * ND;                   // NB*ND

    prep_kernel<<<192, 256, 0, stream>>>(topic_w, fc_u_w, fc_ru_w, fc_i_w, fc_ri_w,
                                         bhi, blo, fuhi, fulo, fihi, filo);
    colsum_kernel<<<1, 256, 0, stream>>>(topic_w, colsum);

    branch_kernel<<<2 * NB, 256, 0, stream>>>(
        user, item, user_r_topic, item_r_topic,
        user_embed_w, item_embed_w, user_att_w, item_att_w,
        bhi, blo, fuhi, fulo, fihi, filo,
        fc_u_b, fc_ru_b, fc_i_b, fc_ri_b,
        h_u_w, h_u_b, h_i_w, h_i_b,
        colsum, u_vec, i_vec);

    final_kernel<<<NB, 64, 0, stream>>>(u_vec, i_vec, fc_pre_w, fc_pre_b,
                                        (float*)d_out);
}

// Round 8
// 179.548 us; speedup vs baseline: 1.3330x; 1.3330x over previous
//
#include <hip/hip_runtime.h>
#include <cstdint>
#include <cstddef>

#define NB 2048
#define NT 512
#define ND 64
#define NR 50
#define NKK 16
#define REVP 68   // review row stride (floats)

typedef __attribute__((ext_vector_type(8))) short bf16x8;
typedef __attribute__((ext_vector_type(4))) float f32x4;

__device__ inline unsigned short f2bf_rne(float x) {
    unsigned int u = __float_as_uint(x);
    u += 0x7fffu + ((u >> 16) & 1u);
    return (unsigned short)(u >> 16);
}

// split 8 f32 -> hi (truncate) / lo (RNE of remainder), packed as bf16x8
__device__ inline void cvt8_fast(float4 v0, float4 v1, bf16x8& ah, bf16x8& al) {
    float f[8] = {v0.x, v0.y, v0.z, v0.w, v1.x, v1.y, v1.z, v1.w};
    union { unsigned int u[4]; bf16x8 v; } H, L;
#pragma unroll
    for (int p = 0; p < 4; ++p) {
        unsigned int u0 = __float_as_uint(f[2*p]);
        unsigned int u1 = __float_as_uint(f[2*p+1]);
        H.u[p] = (u0 >> 16) | (u1 & 0xffff0000u);
        float r0 = f[2*p]   - __uint_as_float(u0 & 0xffff0000u);
        float r1 = f[2*p+1] - __uint_as_float(u1 & 0xffff0000u);
        unsigned int lp;
        asm("v_cvt_pk_bf16_f32 %0, %1, %2" : "=v"(lp) : "v"(r0), "v"(r1));
        L.u[p] = lp;
    }
    ah = H.v; al = L.v;
}

__device__ inline void gload16(const void* gsrc, void* ldst) {
    __builtin_amdgcn_global_load_lds(
        (const __attribute__((address_space(1))) unsigned int*)gsrc,
        (__attribute__((address_space(3))) unsigned int*)ldst, 16, 0, 0);
}

// ---------------------------------------------------------------------------
// Pack topic_w into main-GEMM B-frag order (hi/lo) and fc weights into
// epilogue B-frag order (K=128: rows 0-63 = fc_r_w, 64-127 = fc_a_w).
__global__ __launch_bounds__(256) void prep_kernel(
    const float* __restrict__ tw,
    const float* __restrict__ fc_u_w, const float* __restrict__ fc_ru_w,
    const float* __restrict__ fc_i_w, const float* __restrict__ fc_ri_w,
    unsigned short* __restrict__ bhi, unsigned short* __restrict__ blo,
    unsigned short* __restrict__ fuhi, unsigned short* __restrict__ fulo,
    unsigned short* __restrict__ fihi, unsigned short* __restrict__ filo)
{
    int i = blockIdx.x * 256 + threadIdx.x;          // 192*256 = 49152
    if (i < 32768) {
        int j  = i & 7;
        int l  = (i >> 3) & 63;
        int n  = (i >> 9) & 3;
        int kk = i >> 11;                            // 0..15
        int t = kk * 32 + ((l >> 4) << 3) + j;
        int d = n * 16 + (l & 15);
        float x = tw[t * ND + d];
        unsigned int u = __float_as_uint(x);
        bhi[i] = (unsigned short)(u >> 16);
        blo[i] = f2bf_rne(x - __uint_as_float(u & 0xffff0000u));
    } else {
        int q = i - 32768;                           // 0..16383
        int br = q >> 13;                            // 0 user, 1 item
        int e = q & 8191;
        int j  = e & 7;
        int l  = (e >> 3) & 63;
        int n  = (e >> 9) & 3;
        int kk = e >> 11;                            // 0..3
        int k = kk * 32 + ((l >> 4) << 3) + j;       // 0..127
        int col = n * 16 + (l & 15);
        const float* W = (k < 64) ? (br ? fc_ri_w : fc_ru_w)
                                  : (br ? fc_i_w  : fc_u_w);
        float x = W[(k & 63) * ND + col];
        unsigned int u = __float_as_uint(x);
        unsigned short hi = (unsigned short)(u >> 16);
        unsigned short lo = f2bf_rne(x - __uint_as_float(u & 0xffff0000u));
        if (br) { fihi[e] = hi; filo[e] = lo; }
        else    { fuhi[e] = hi; fulo[e] = lo; }
    }
}

// ---------------------------------------------------------------------------
__global__ __launch_bounds__(256) void colsum_kernel(const float* __restrict__ tw,
                                                     float* __restrict__ colsum) {
    __shared__ float part[4][ND];
    int d = threadIdx.x & 63, p = threadIdx.x >> 6;
    float s = 0.f;
    for (int t = p; t < NT; t += 4) s += tw[t * ND + d];
    part[p][d] = s;
    __syncthreads();
    if (threadIdx.x < ND)
        colsum[d] = part[0][d] + part[1][d] + part[2][d] + part[3][d];
}

// ---------------------------------------------------------------------------
// One block per (branch, batch element). 4 waves.
// Ring-3 LDS double... triple-buffer with COUNTED vmcnt (never 0 in loop):
//   iter t: s_waitcnt vmcnt(4) -> stage(t) landed (t+1 stays in flight)
//           s_barrier           -> all waves' stage(t) landed, compute(t-1) done
//           stage(t+2)          -> into buffer freed by compute(t-1)
//           compute(t)
__global__ __launch_bounds__(256, 3) void branch_kernel(
    const int* __restrict__ user, const int* __restrict__ item,
    const float* __restrict__ user_r_topic, const float* __restrict__ item_r_topic,
    const float* __restrict__ user_embed_w, const float* __restrict__ item_embed_w,
    const float* __restrict__ user_att_w, const float* __restrict__ item_att_w,
    const unsigned short* __restrict__ bhi, const unsigned short* __restrict__ blo,
    const unsigned short* __restrict__ fuhi, const unsigned short* __restrict__ fulo,
    const unsigned short* __restrict__ fihi, const unsigned short* __restrict__ filo,
    const float* __restrict__ fc_u_b, const float* __restrict__ fc_ru_b,
    const float* __restrict__ fc_i_b, const float* __restrict__ fc_ri_b,
    const float* __restrict__ h_u_w, const float* __restrict__ h_u_b,
    const float* __restrict__ h_i_w, const float* __restrict__ h_i_b,
    const float* __restrict__ colsum,
    float* __restrict__ u_vec, float* __restrict__ i_vec)
{
    const int bb = blockIdx.x;
    const int branch = bb >> 11;          // 0 = user, 1 = item
    const int b = bb & (NB - 1);

    const int*   ids     = branch ? item           : user;
    const float* r_topic = branch ? item_r_topic   : user_r_topic;
    const float* emb_w   = branch ? item_embed_w   : user_embed_w;
    const float* att_w   = branch ? item_att_w     : user_att_w;
    const unsigned short* fhi = branch ? fihi : fuhi;
    const unsigned short* flo = branch ? filo : fulo;
    const float* fc_a_b  = branch ? fc_i_b         : fc_u_b;
    const float* fc_r_b  = branch ? fc_ri_b        : fc_ru_b;
    const float* h_w     = branch ? h_i_w          : h_u_w;
    const float* h_b     = branch ? h_i_b          : h_u_b;
    float*       out_vec = branch ? i_vec          : u_vec;

    // arena: A ring3 at 0/8K/16K ; B ring3 at 24K/32K/40K (hi 4K + lo 4K each)
    // epilogue overlays rev[50][68] (13.6 KB) on bytes [0, 13600)
    __shared__ __align__(16) unsigned char arena[49152];
    __shared__ float lds_logit[NR + 2];

    const int tid = threadIdx.x, wave = tid >> 6, lane = tid & 63;
    const int g = lane >> 4, c16 = lane & 15;
    const int id = ids[b];

    const float* Abase = r_topic + (size_t)b * NR * NT;

    // per-wave per-stage: 2 A-instrs + 2 B-instrs = 4 vmem ops, 4 KB
    auto stageA = [&](int kk, unsigned char* ab) {
#pragma unroll
        for (int i = 0; i < 2; ++i) {
            int s = wave * 2 + i;
            int cid = s * 64 + lane;          // LDS 16B-chunk id
            int row = cid >> 3;
            int slot = cid & 7;
            int d = (slot - row) & 7;         // XOR-ish swizzled placement
            int rc = row < NR ? row : NR - 1; // clamp pad rows
            const float* src = Abase + (size_t)rc * NT + kk * 32 + (d >> 1) * 8 + (d & 1) * 4;
            gload16(src, ab + s * 1024);
        }
    };
    auto stageB = [&](int kk, unsigned char* bbp) {
        const unsigned char* sh = (const unsigned char*)bhi + (size_t)kk * 4096 + wave * 1024 + (size_t)lane * 16;
        gload16(sh, bbp + wave * 1024);
        const unsigned char* sl = (const unsigned char*)blo + (size_t)kk * 4096 + wave * 1024 + (size_t)lane * 16;
        gload16(sl, bbp + 4096 + wave * 1024);
    };

    f32x4 acc[4];
#pragma unroll
    for (int n = 0; n < 4; ++n) acc[n] = (f32x4){0.f, 0.f, 0.f, 0.f};

    // prologue: stages 0 and 1 in flight (8 vmem ops/wave)
    stageA(0, arena);         stageB(0, arena + 24576);
    stageA(1, arena + 8192);  stageB(1, arena + 24576 + 8192);

    const int rowm = wave * 16 + c16;         // this lane's M row (0..63)
    int o_cur = 0, o_nxt = 8192, o_nx2 = 16384;

    for (int t = 0; t < NKK; ++t) {
        // counted wait: stage(t) landed; stage(t+1) (4 ops) may stay in flight
        if (t < NKK - 1) asm volatile("s_waitcnt vmcnt(4)" ::: "memory");
        else             asm volatile("s_waitcnt vmcnt(0)" ::: "memory");
        __builtin_amdgcn_s_barrier();   // all waves: buf(t) ready, buf(t-1) reads done

        if (t + 2 < NKK) {              // refill buffer freed by compute(t-1)
            stageA(t + 2, arena + o_nx2);
            stageB(t + 2, arena + 24576 + o_nx2);
        }

        // compute step t from buf(t)
        const unsigned char* ab  = arena + o_cur;
        const unsigned char* bbf = arena + 24576 + o_cur;
        float4 a0 = *reinterpret_cast<const float4*>(ab + (rowm * 8 + ((g * 2 + rowm) & 7)) * 16);
        float4 a1 = *reinterpret_cast<const float4*>(ab + (rowm * 8 + ((g * 2 + 1 + rowm) & 7)) * 16);
        bf16x8 ah, al;
        cvt8_fast(a0, a1, ah, al);
#pragma unroll
        for (int n = 0; n < 4; ++n) {
            bf16x8 bh = *reinterpret_cast<const bf16x8*>(bbf + (n * 64 + lane) * 16);
            bf16x8 bl = *reinterpret_cast<const bf16x8*>(bbf + 4096 + (n * 64 + lane) * 16);
            acc[n] = __builtin_amdgcn_mfma_f32_16x16x32_bf16(ah, bh, acc[n], 0, 0, 0);
            acc[n] = __builtin_amdgcn_mfma_f32_16x16x32_bf16(al, bh, acc[n], 0, 0, 0);
            acc[n] = __builtin_amdgcn_mfma_f32_16x16x32_bf16(ah, bl, acc[n], 0, 0, 0);
        }

        int tmp = o_cur; o_cur = o_nxt; o_nxt = o_nx2; o_nx2 = tmp;
    }

    __syncthreads();                    // all waves done reading arena buffers
    float (*rev)[REVP] = reinterpret_cast<float(*)[REVP]>(arena);
#pragma unroll
    for (int n = 0; n < 4; ++n)
#pragma unroll
        for (int r4 = 0; r4 < 4; ++r4) {
            int r = wave * 16 + g * 4 + r4;
            if (r < NR) rev[r][n * 16 + c16] = acc[n][r4];
        }
    // no barrier: epilogue reads only this wave's own rows

    // ---- epilogue s-matmul: s[50x64] = review@fcR + att@fcA (K=128) ----
    const int rowc = rowm < NR ? rowm : NR - 1;
    f32x4 s4[4];
#pragma unroll
    for (int n = 0; n < 4; ++n) s4[n] = (f32x4){0.f, 0.f, 0.f, 0.f};

#pragma unroll
    for (int kk2 = 0; kk2 < 4; ++kk2) {
        bf16x8 bh[4], bl[4];
#pragma unroll
        for (int n = 0; n < 4; ++n) {
            bh[n] = *(reinterpret_cast<const bf16x8*>(fhi + (size_t)(kk2 * 4 + n) * 512) + lane);
            bl[n] = *(reinterpret_cast<const bf16x8*>(flo + (size_t)(kk2 * 4 + n) * 512) + lane);
        }
        bf16x8 ah, al;
        if (kk2 < 2) {
            const float* rp = &rev[rowc][kk2 * 32 + g * 8];
            cvt8_fast(*reinterpret_cast<const float4*>(rp),
                      *reinterpret_cast<const float4*>(rp + 4), ah, al);
        } else {
            const float* ap = att_w + (size_t)id * ND + (kk2 - 2) * 32 + g * 8;
            cvt8_fast(*reinterpret_cast<const float4*>(ap),
                      *reinterpret_cast<const float4*>(ap + 4), ah, al);
        }
#pragma unroll
        for (int n = 0; n < 4; ++n) {
            s4[n] = __builtin_amdgcn_mfma_f32_16x16x32_bf16(ah, bh[n], s4[n], 0, 0, 0);
            s4[n] = __builtin_amdgcn_mfma_f32_16x16x32_bf16(al, bh[n], s4[n], 0, 0, 0);
            s4[n] = __builtin_amdgcn_mfma_f32_16x16x32_bf16(ah, bl[n], s4[n], 0, 0, 0);
        }
    }

    // bias + relu + dot with h_w, then 16-lane reduce -> logits
    const float hb = h_b[0];
    float p0 = 0.f, p1 = 0.f, p2 = 0.f, p3 = 0.f;
#pragma unroll
    for (int n = 0; n < 4; ++n) {
        float hwn = h_w[n * 16 + c16];
        float bs = fc_r_b[n * 16 + c16] + fc_a_b[n * 16 + c16];
        p0 = fmaf(fmaxf(s4[n][0] + bs, 0.f), hwn, p0);
        p1 = fmaf(fmaxf(s4[n][1] + bs, 0.f), hwn, p1);
        p2 = fmaf(fmaxf(s4[n][2] + bs, 0.f), hwn, p2);
        p3 = fmaf(fmaxf(s4[n][3] + bs, 0.f), hwn, p3);
    }
#pragma unroll
    for (int off = 1; off < 16; off <<= 1) {
        p0 += __shfl_xor(p0, off);
        p1 += __shfl_xor(p1, off);
        p2 += __shfl_xor(p2, off);
        p3 += __shfl_xor(p3, off);
    }
    if (c16 == 0) {
        int rb = wave * 16 + g * 4;
        if (rb + 0 < NR) lds_logit[rb + 0] = p0 + hb;
        if (rb + 1 < NR) lds_logit[rb + 1] = p1 + hb;
        if (rb + 2 < NR) lds_logit[rb + 2] = p2 + hb;
        if (rb + 3 < NR) lds_logit[rb + 3] = p3 + hb;
    }
    __syncthreads();   // publish rev rows + logits to wave 0

    // softmax + pooling + colsum scale + emb add (wave 0)
    if (wave == 0) {
        float m = -1e30f;
        for (int r = 0; r < NR; ++r) m = fmaxf(m, lds_logit[r]);
        float sum = 0.f;
        for (int r = 0; r < NR; ++r) sum += __expf(lds_logit[r] - m);
        float inv = 1.f / sum;
        float feat = 0.f;
        for (int r = 0; r < NR; ++r)
            feat = fmaf(__expf(lds_logit[r] - m), rev[r][lane], feat);
        feat *= inv;
        out_vec[(size_t)b * ND + lane] = feat * colsum[lane] + emb_w[(size_t)id * ND + lane];
    }
}

// ---------------------------------------------------------------------------
__global__ __launch_bounds__(64) void final_kernel(
    const float* __restrict__ u_vec, const float* __restrict__ i_vec,
    const float* __restrict__ fc_pre_w, const float* __restrict__ fc_pre_b,
    float* __restrict__ out)
{
    int b = blockIdx.x, lane = threadIdx.x;
    float v = u_vec[(size_t)b * ND + lane] * fc_pre_w[lane]
            + i_vec[(size_t)b * ND + lane] * fc_pre_w[ND + lane];
#pragma unroll
    for (int off = 32; off; off >>= 1) v += __shfl_xor(v, off);
    if (lane == 0) out[b] = fmaxf(v + fc_pre_b[0], 0.f);
}

// ---------------------------------------------------------------------------
extern "C" void kernel_launch(void* const* d_in, const int* in_sizes, int n_in,
                              void* d_out, int out_size, void* d_ws, size_t ws_size,
                              hipStream_t stream) {
    (void)in_sizes; (void)n_in; (void)out_size; (void)ws_size;

    const int*   user         = (const int*)d_in[0];
    const int*   item         = (const int*)d_in[1];
    const float* user_r_topic = (const float*)d_in[2];
    const float* item_r_topic = (const float*)d_in[3];
    const float* user_embed_w = (const float*)d_in[4];
    const float* item_embed_w = (const float*)d_in[5];
    const float* user_att_w   = (const float*)d_in[6];
    const float* item_att_w   = (const float*)d_in[7];
    const float* topic_w      = (const float*)d_in[8];
    const float* fc_u_w       = (const float*)d_in[9];
    const float* fc_u_b       = (const float*)d_in[10];
    const float* fc_ru_w      = (const float*)d_in[11];
    const float* fc_ru_b      = (const float*)d_in[12];
    const float* fc_i_w       = (const float*)d_in[13];
    const float* fc_i_b       = (const float*)d_in[14];
    const float* fc_ri_w      = (const float*)d_in[15];
    const float* fc_ri_b      = (const float*)d_in[16];
    const float* h_u_w        = (const float*)d_in[17];
    const float* h_u_b        = (const float*)d_in[18];
    const float* h_i_w        = (const float*)d_in[19];
    const float* h_i_b        = (const float*)d_in[20];
    const float* fc_pre_w     = (const float*)d_in[21];
    const float* fc_pre_b     = (const float*)d_in[22];

    // workspace layout
    unsigned short* bhi  = (unsigned short*)d_ws;      // 32768
    unsigned short* blo  = bhi + 32768;                // 32768
    unsigned short* fuhi = blo + 32768;                // 8192
    unsigned short* fulo = fuhi + 8192;
    unsigned short* fihi = fulo + 8192;
    unsigned short* filo = fihi + 8192;
    float* colsum = (float*)(filo + 8192);             // 64
    float* u_vec  = colsum + 64;                       // NB*ND
    float* i_vec  = u_vec + NB * ND;                   // NB*ND

    prep_kernel<<<192, 256, 0, stream>>>(topic_w, fc_u_w, fc_ru_w, fc_i_w, fc_ri_w,
                                         bhi, blo, fuhi, fulo, fihi, filo);
    colsum_kernel<<<1, 256, 0, stream>>>(topic_w, colsum);

    branch_kernel<<<2 * NB, 256, 0, stream>>>(
        user, item, user_r_topic, item_r_topic,
        user_embed_w, item_embed_w, user_att_w, item_att_w,
        bhi, blo, fuhi, fulo, fihi, filo,
        fc_u_b, fc_ru_b, fc_i_b, fc_ri_b,
        h_u_w, h_u_b, h_i_w, h_i_b,
        colsum, u_vec, i_vec);

    final_kernel<<<NB, 64, 0, stream>>>(u_vec, i_vec, fc_pre_w, fc_pre_b,
                                        (float*)d_out);
}

// Round 9
// 161.123 us; speedup vs baseline: 1.4854x; 1.1143x over previous
//
#include <hip/hip_runtime.h>
#include <cstdint>
#include <cstddef>

#define NB 2048
#define NT 512
#define ND 64
#define NR 50
#define NKK 16
#define REVP 68   // review row stride (floats)

typedef __attribute__((ext_vector_type(8))) short bf16x8;
typedef __attribute__((ext_vector_type(4))) float f32x4;

__device__ inline unsigned short f2bf_rne(float x) {
    unsigned int u = __float_as_uint(x);
    u += 0x7fffu + ((u >> 16) & 1u);
    return (unsigned short)(u >> 16);
}

// split 8 f32 -> hi (truncate) / lo (RNE of remainder), packed as bf16x8
__device__ inline void cvt8_fast(float4 v0, float4 v1, bf16x8& ah, bf16x8& al) {
    float f[8] = {v0.x, v0.y, v0.z, v0.w, v1.x, v1.y, v1.z, v1.w};
    union { unsigned int u[4]; bf16x8 v; } H, L;
#pragma unroll
    for (int p = 0; p < 4; ++p) {
        unsigned int u0 = __float_as_uint(f[2*p]);
        unsigned int u1 = __float_as_uint(f[2*p+1]);
        H.u[p] = (u0 >> 16) | (u1 & 0xffff0000u);
        float r0 = f[2*p]   - __uint_as_float(u0 & 0xffff0000u);
        float r1 = f[2*p+1] - __uint_as_float(u1 & 0xffff0000u);
        unsigned int lp;
        asm("v_cvt_pk_bf16_f32 %0, %1, %2" : "=v"(lp) : "v"(r0), "v"(r1));
        L.u[p] = lp;
    }
    ah = H.v; al = L.v;
}

__device__ inline void gload16(const void* gsrc, void* ldst) {
    __builtin_amdgcn_global_load_lds(
        (const __attribute__((address_space(1))) unsigned int*)gsrc,
        (__attribute__((address_space(3))) unsigned int*)ldst, 16, 0, 0);
}

// ---------------------------------------------------------------------------
// Pack topic_w into main-GEMM B-frag order (hi/lo) and fc weights into
// epilogue B-frag order (K=128: rows 0-63 = fc_r_w, 64-127 = fc_a_w).
__global__ __launch_bounds__(256) void prep_kernel(
    const float* __restrict__ tw,
    const float* __restrict__ fc_u_w, const float* __restrict__ fc_ru_w,
    const float* __restrict__ fc_i_w, const float* __restrict__ fc_ri_w,
    unsigned short* __restrict__ bhi, unsigned short* __restrict__ blo,
    unsigned short* __restrict__ fuhi, unsigned short* __restrict__ fulo,
    unsigned short* __restrict__ fihi, unsigned short* __restrict__ filo)
{
    int i = blockIdx.x * 256 + threadIdx.x;          // 192*256 = 49152
    if (i < 32768) {
        int j  = i & 7;
        int l  = (i >> 3) & 63;
        int n  = (i >> 9) & 3;
        int kk = i >> 11;                            // 0..15
        int t = kk * 32 + ((l >> 4) << 3) + j;
        int d = n * 16 + (l & 15);
        float x = tw[t * ND + d];
        unsigned int u = __float_as_uint(x);
        bhi[i] = (unsigned short)(u >> 16);
        blo[i] = f2bf_rne(x - __uint_as_float(u & 0xffff0000u));
    } else {
        int q = i - 32768;                           // 0..16383
        int br = q >> 13;                            // 0 user, 1 item
        int e = q & 8191;
        int j  = e & 7;
        int l  = (e >> 3) & 63;
        int n  = (e >> 9) & 3;
        int kk = e >> 11;                            // 0..3
        int k = kk * 32 + ((l >> 4) << 3) + j;       // 0..127
        int col = n * 16 + (l & 15);
        const float* W = (k < 64) ? (br ? fc_ri_w : fc_ru_w)
                                  : (br ? fc_i_w  : fc_u_w);
        float x = W[(k & 63) * ND + col];
        unsigned int u = __float_as_uint(x);
        unsigned short hi = (unsigned short)(u >> 16);
        unsigned short lo = f2bf_rne(x - __uint_as_float(u & 0xffff0000u));
        if (br) { fihi[e] = hi; filo[e] = lo; }
        else    { fuhi[e] = hi; fulo[e] = lo; }
    }
}

// ---------------------------------------------------------------------------
__global__ __launch_bounds__(256) void colsum_kernel(const float* __restrict__ tw,
                                                     float* __restrict__ colsum) {
    __shared__ float part[4][ND];
    int d = threadIdx.x & 63, p = threadIdx.x >> 6;
    float s = 0.f;
    for (int t = p; t < NT; t += 4) s += tw[t * ND + d];
    part[p][d] = s;
    __syncthreads();
    if (threadIdx.x < ND)
        colsum[d] = part[0][d] + part[1][d] + part[2][d] + part[3][d];
}

// ---------------------------------------------------------------------------
// One block = 2 batch elements, 8 waves (waves 0-3 -> elem0, 4-7 -> elem1).
// B staged ONCE per K-half into LDS (2 barriers total). A: global->register,
// ZERO barriers in K loop -> 8 independent wave streams; TLP hides latency.
__global__ __launch_bounds__(512, 4) void branch_kernel(
    const int* __restrict__ user, const int* __restrict__ item,
    const float* __restrict__ user_r_topic, const float* __restrict__ item_r_topic,
    const float* __restrict__ user_embed_w, const float* __restrict__ item_embed_w,
    const float* __restrict__ user_att_w, const float* __restrict__ item_att_w,
    const unsigned short* __restrict__ bhi, const unsigned short* __restrict__ blo,
    const unsigned short* __restrict__ fuhi, const unsigned short* __restrict__ fulo,
    const unsigned short* __restrict__ fihi, const unsigned short* __restrict__ filo,
    const float* __restrict__ fc_u_b, const float* __restrict__ fc_ru_b,
    const float* __restrict__ fc_i_b, const float* __restrict__ fc_ri_b,
    const float* __restrict__ h_u_w, const float* __restrict__ h_u_b,
    const float* __restrict__ h_i_w, const float* __restrict__ h_i_b,
    const float* __restrict__ colsum,
    float* __restrict__ u_vec, float* __restrict__ i_vec)
{
    // arena: B-half hi [0,32K) + lo [32K,64K). rev[2][50][68] overlays [0,27.2K)
    __shared__ __align__(16) unsigned char arena[65536];
    __shared__ float lds_logit[2][NR + 2];

    const int tid = threadIdx.x, wave = tid >> 6, lane = tid & 63;
    const int g = lane >> 4, c16 = lane & 15;
    const int e = wave >> 2, sw = wave & 3;

    const int E = blockIdx.x * 2 + e;       // global elem id
    const int branch = E >> 11;             // 0 = user, 1 = item
    const int b = E & (NB - 1);

    const int*   ids     = branch ? item           : user;
    const float* r_topic = branch ? item_r_topic   : user_r_topic;
    const float* emb_w   = branch ? item_embed_w   : user_embed_w;
    const float* att_w   = branch ? item_att_w     : user_att_w;
    const unsigned short* fhi = branch ? fihi : fuhi;
    const unsigned short* flo = branch ? filo : fulo;
    const float* fc_a_b  = branch ? fc_i_b         : fc_u_b;
    const float* fc_r_b  = branch ? fc_ri_b        : fc_ru_b;
    const float* h_w     = branch ? h_i_w          : h_u_w;
    const float* h_b     = branch ? h_i_b          : h_u_b;
    float*       out_vec = branch ? i_vec          : u_vec;

    const int id = ids[b];
    const int rowm = sw * 16 + c16;
    const int rowc = rowm < NR ? rowm : NR - 1;
    const float* arow = r_topic + (size_t)b * NR * NT + (size_t)rowc * NT + g * 8;

    // stage one 64KB B-half (hi+lo) with all 512 threads
    auto stageB = [&](int h) {
        const unsigned char* srcH = (const unsigned char*)bhi + (size_t)h * 32768;
        const unsigned char* srcL = (const unsigned char*)blo + (size_t)h * 32768;
#pragma unroll
        for (int i = 0; i < 4; ++i) {
            size_t off = (size_t)(i * 512 + tid) * 16;
            gload16(srcH + off, arena + off);
            gload16(srcL + off, arena + 32768 + off);
        }
    };

    f32x4 acc[4];
#pragma unroll
    for (int n = 0; n < 4; ++n) acc[n] = (f32x4){0.f, 0.f, 0.f, 0.f};

    for (int h = 0; h < 2; ++h) {
        stageB(h);
        asm volatile("s_waitcnt vmcnt(0)" ::: "memory");
        __builtin_amdgcn_s_barrier();       // B-half ready for all waves

#pragma unroll 2
        for (int kloc = 0; kloc < 8; ++kloc) {
            const int kk = h * 8 + kloc;
            float4 a0 = *reinterpret_cast<const float4*>(arow + kk * 32);
            float4 a1 = *reinterpret_cast<const float4*>(arow + kk * 32 + 4);
            bf16x8 ah, al;
            cvt8_fast(a0, a1, ah, al);
#pragma unroll
            for (int n = 0; n < 4; ++n) {
                const unsigned char* p = arena + (size_t)((kloc * 4 + n) * 64 + lane) * 16;
                bf16x8 bh = *reinterpret_cast<const bf16x8*>(p);
                bf16x8 bl = *reinterpret_cast<const bf16x8*>(p + 32768);
                acc[n] = __builtin_amdgcn_mfma_f32_16x16x32_bf16(ah, bh, acc[n], 0, 0, 0);
                acc[n] = __builtin_amdgcn_mfma_f32_16x16x32_bf16(al, bh, acc[n], 0, 0, 0);
                acc[n] = __builtin_amdgcn_mfma_f32_16x16x32_bf16(ah, bl, acc[n], 0, 0, 0);
            }
        }
        __builtin_amdgcn_s_barrier();       // all waves done reading this half
    }

    // rev overlay on arena (B no longer needed)
    float (*rev)[NR][REVP] = reinterpret_cast<float(*)[NR][REVP]>(arena);
#pragma unroll
    for (int n = 0; n < 4; ++n)
#pragma unroll
        for (int r4 = 0; r4 < 4; ++r4) {
            int r = sw * 16 + g * 4 + r4;
            if (r < NR) rev[e][r][n * 16 + c16] = acc[n][r4];
        }
    // no barrier: epilogue reads only this wave's own rows

    // ---- epilogue s-matmul: s[50x64] = review@fcR + att@fcA (K=128) ----
    f32x4 s4[4];
#pragma unroll
    for (int n = 0; n < 4; ++n) s4[n] = (f32x4){0.f, 0.f, 0.f, 0.f};

#pragma unroll
    for (int kk2 = 0; kk2 < 4; ++kk2) {
        bf16x8 bh[4], bl[4];
#pragma unroll
        for (int n = 0; n < 4; ++n) {
            bh[n] = *(reinterpret_cast<const bf16x8*>(fhi + (size_t)(kk2 * 4 + n) * 512) + lane);
            bl[n] = *(reinterpret_cast<const bf16x8*>(flo + (size_t)(kk2 * 4 + n) * 512) + lane);
        }
        bf16x8 ah, al;
        if (kk2 < 2) {
            const float* rp = &rev[e][rowc][kk2 * 32 + g * 8];
            cvt8_fast(*reinterpret_cast<const float4*>(rp),
                      *reinterpret_cast<const float4*>(rp + 4), ah, al);
        } else {
            const float* ap = att_w + (size_t)id * ND + (kk2 - 2) * 32 + g * 8;
            cvt8_fast(*reinterpret_cast<const float4*>(ap),
                      *reinterpret_cast<const float4*>(ap + 4), ah, al);
        }
#pragma unroll
        for (int n = 0; n < 4; ++n) {
            s4[n] = __builtin_amdgcn_mfma_f32_16x16x32_bf16(ah, bh[n], s4[n], 0, 0, 0);
            s4[n] = __builtin_amdgcn_mfma_f32_16x16x32_bf16(al, bh[n], s4[n], 0, 0, 0);
            s4[n] = __builtin_amdgcn_mfma_f32_16x16x32_bf16(ah, bl[n], s4[n], 0, 0, 0);
        }
    }

    // bias + relu + dot with h_w, then 16-lane reduce -> logits
    const float hb = h_b[0];
    float p0 = 0.f, p1 = 0.f, p2 = 0.f, p3 = 0.f;
#pragma unroll
    for (int n = 0; n < 4; ++n) {
        float hwn = h_w[n * 16 + c16];
        float bs = fc_r_b[n * 16 + c16] + fc_a_b[n * 16 + c16];
        p0 = fmaf(fmaxf(s4[n][0] + bs, 0.f), hwn, p0);
        p1 = fmaf(fmaxf(s4[n][1] + bs, 0.f), hwn, p1);
        p2 = fmaf(fmaxf(s4[n][2] + bs, 0.f), hwn, p2);
        p3 = fmaf(fmaxf(s4[n][3] + bs, 0.f), hwn, p3);
    }
#pragma unroll
    for (int off = 1; off < 16; off <<= 1) {
        p0 += __shfl_xor(p0, off);
        p1 += __shfl_xor(p1, off);
        p2 += __shfl_xor(p2, off);
        p3 += __shfl_xor(p3, off);
    }
    if (c16 == 0) {
        int rb = sw * 16 + g * 4;
        if (rb + 0 < NR) lds_logit[e][rb + 0] = p0 + hb;
        if (rb + 1 < NR) lds_logit[e][rb + 1] = p1 + hb;
        if (rb + 2 < NR) lds_logit[e][rb + 2] = p2 + hb;
        if (rb + 3 < NR) lds_logit[e][rb + 3] = p3 + hb;
    }
    __syncthreads();   // publish rev rows + logits

    // softmax + pooling + colsum scale + emb add (wave 0 -> elem0, wave 4 -> elem1)
    if (sw == 0) {
        float m = -1e30f;
        for (int r = 0; r < NR; ++r) m = fmaxf(m, lds_logit[e][r]);
        float sum = 0.f;
        for (int r = 0; r < NR; ++r) sum += __expf(lds_logit[e][r] - m);
        float inv = 1.f / sum;
        float feat = 0.f;
        for (int r = 0; r < NR; ++r)
            feat = fmaf(__expf(lds_logit[e][r] - m), rev[e][r][lane], feat);
        feat *= inv;
        out_vec[(size_t)b * ND + lane] = feat * colsum[lane] + emb_w[(size_t)id * ND + lane];
    }
}

// ---------------------------------------------------------------------------
__global__ __launch_bounds__(64) void final_kernel(
    const float* __restrict__ u_vec, const float* __restrict__ i_vec,
    const float* __restrict__ fc_pre_w, const float* __restrict__ fc_pre_b,
    float* __restrict__ out)
{
    int b = blockIdx.x, lane = threadIdx.x;
    float v = u_vec[(size_t)b * ND + lane] * fc_pre_w[lane]
            + i_vec[(size_t)b * ND + lane] * fc_pre_w[ND + lane];
#pragma unroll
    for (int off = 32; off; off >>= 1) v += __shfl_xor(v, off);
    if (lane == 0) out[b] = fmaxf(v + fc_pre_b[0], 0.f);
}

// ---------------------------------------------------------------------------
extern "C" void kernel_launch(void* const* d_in, const int* in_sizes, int n_in,
                              void* d_out, int out_size, void* d_ws, size_t ws_size,
                              hipStream_t stream) {
    (void)in_sizes; (void)n_in; (void)out_size; (void)ws_size;

    const int*   user         = (const int*)d_in[0];
    const int*   item         = (const int*)d_in[1];
    const float* user_r_topic = (const float*)d_in[2];
    const float* item_r_topic = (const float*)d_in[3];
    const float* user_embed_w = (const float*)d_in[4];
    const float* item_embed_w = (const float*)d_in[5];
    const float* user_att_w   = (const float*)d_in[6];
    const float* item_att_w   = (const float*)d_in[7];
    const float* topic_w      = (const float*)d_in[8];
    const float* fc_u_w       = (const float*)d_in[9];
    const float* fc_u_b       = (const float*)d_in[10];
    const float* fc_ru_w      = (const float*)d_in[11];
    const float* fc_ru_b      = (const float*)d_in[12];
    const float* fc_i_w       = (const float*)d_in[13];
    const float* fc_i_b       = (const float*)d_in[14];
    const float* fc_ri_w      = (const float*)d_in[15];
    const float* fc_ri_b      = (const float*)d_in[16];
    const float* h_u_w        = (const float*)d_in[17];
    const float* h_u_b        = (const float*)d_in[18];
    const float* h_i_w        = (const float*)d_in[19];
    const float* h_i_b        = (const float*)d_in[20];
    const float* fc_pre_w     = (const float*)d_in[21];
    const float* fc_pre_b     = (const float*)d_in[22];

    // workspace layout
    unsigned short* bhi  = (unsigned short*)d_ws;      // 32768
    unsigned short* blo  = bhi + 32768;                // 32768
    unsigned short* fuhi = blo + 32768;                // 8192
    unsigned short* fulo = fuhi + 8192;
    unsigned short* fihi = fulo + 8192;
    unsigned short* filo = fihi + 8192;
    float* colsum = (float*)(filo + 8192);             // 64
    float* u_vec  = colsum + 64;                       // NB*ND
    float* i_vec  = u_vec + NB * ND;                   // NB*ND

    prep_kernel<<<192, 256, 0, stream>>>(topic_w, fc_u_w, fc_ru_w, fc_i_w, fc_ri_w,
                                         bhi, blo, fuhi, fulo, fihi, filo);
    colsum_kernel<<<1, 256, 0, stream>>>(topic_w, colsum);

    branch_kernel<<<NB, 512, 0, stream>>>(
        user, item, user_r_topic, item_r_topic,
        user_embed_w, item_embed_w, user_att_w, item_att_w,
        bhi, blo, fuhi, fulo, fihi, filo,
        fc_u_b, fc_ru_b, fc_i_b, fc_ri_b,
        h_u_w, h_u_b, h_i_w, h_i_b,
        colsum, u_vec, i_vec);

    final_kernel<<<NB, 64, 0, stream>>>(u_vec, i_vec, fc_pre_w, fc_pre_b,
                                        (float*)d_out);
}

// Round 11
// 150.915 us; speedup vs baseline: 1.5859x; 1.0676x over previous
//
#include <hip/hip_runtime.h>
#include <cstdint>
#include <cstddef>

#define NB 2048
#define NT 512
#define ND 64
#define NR 50
#define NKK 16
#define NE 2      // batch elements per block
#define REVP 68   // review row stride (floats)

typedef __attribute__((ext_vector_type(8))) short bf16x8;
typedef __attribute__((ext_vector_type(4))) float f32x4;

__device__ inline unsigned short f2bf_rne(float x) {
    unsigned int u = __float_as_uint(x);
    u += 0x7fffu + ((u >> 16) & 1u);
    return (unsigned short)(u >> 16);
}

// split 8 f32 -> hi (truncate) / lo (RNE of remainder), packed as bf16x8
__device__ inline void cvt8_fast(float4 v0, float4 v1, bf16x8& ah, bf16x8& al) {
    float f[8] = {v0.x, v0.y, v0.z, v0.w, v1.x, v1.y, v1.z, v1.w};
    union { unsigned int u[4]; bf16x8 v; } H, L;
#pragma unroll
    for (int p = 0; p < 4; ++p) {
        unsigned int u0 = __float_as_uint(f[2*p]);
        unsigned int u1 = __float_as_uint(f[2*p+1]);
        H.u[p] = (u0 >> 16) | (u1 & 0xffff0000u);
        float r0 = f[2*p]   - __uint_as_float(u0 & 0xffff0000u);
        float r1 = f[2*p+1] - __uint_as_float(u1 & 0xffff0000u);
        unsigned int lp;
        asm("v_cvt_pk_bf16_f32 %0, %1, %2" : "=v"(lp) : "v"(r0), "v"(r1));
        L.u[p] = lp;
    }
    ah = H.v; al = L.v;
}

// PINNED global load: compiler cannot sink/remat/reorder an inline-asm.
__device__ inline float4 gload4_pin(const float* p) {
    float4 d;
    asm volatile("global_load_dwordx4 %0, %1, off"
                 : "=v"(d) : "v"(p) : "memory");
    return d;
}

__device__ inline void gload16(const void* gsrc, void* ldst) {
    __builtin_amdgcn_global_load_lds(
        (const __attribute__((address_space(1))) unsigned int*)gsrc,
        (__attribute__((address_space(3))) unsigned int*)ldst, 16, 0, 0);
}

// ---------------------------------------------------------------------------
// Pack topic_w into main-GEMM B-frag order (hi/lo) and fc weights into
// epilogue B-frag order (K=128: rows 0-63 = fc_r_w, 64-127 = fc_a_w).
__global__ __launch_bounds__(256) void prep_kernel(
    const float* __restrict__ tw,
    const float* __restrict__ fc_u_w, const float* __restrict__ fc_ru_w,
    const float* __restrict__ fc_i_w, const float* __restrict__ fc_ri_w,
    unsigned short* __restrict__ bhi, unsigned short* __restrict__ blo,
    unsigned short* __restrict__ fuhi, unsigned short* __restrict__ fulo,
    unsigned short* __restrict__ fihi, unsigned short* __restrict__ filo)
{
    int i = blockIdx.x * 256 + threadIdx.x;          // 192*256 = 49152
    if (i < 32768) {
        int j  = i & 7;
        int l  = (i >> 3) & 63;
        int n  = (i >> 9) & 3;
        int kk = i >> 11;                            // 0..15
        int t = kk * 32 + ((l >> 4) << 3) + j;
        int d = n * 16 + (l & 15);
        float x = tw[t * ND + d];
        unsigned int u = __float_as_uint(x);
        bhi[i] = (unsigned short)(u >> 16);
        blo[i] = f2bf_rne(x - __uint_as_float(u & 0xffff0000u));
    } else {
        int q = i - 32768;                           // 0..16383
        int br = q >> 13;                            // 0 user, 1 item
        int e = q & 8191;
        int j  = e & 7;
        int l  = (e >> 3) & 63;
        int n  = (e >> 9) & 3;
        int kk = e >> 11;                            // 0..3
        int k = kk * 32 + ((l >> 4) << 3) + j;       // 0..127
        int col = n * 16 + (l & 15);
        const float* W = (k < 64) ? (br ? fc_ri_w : fc_ru_w)
                                  : (br ? fc_i_w  : fc_u_w);
        float x = W[(k & 63) * ND + col];
        unsigned int u = __float_as_uint(x);
        unsigned short hi = (unsigned short)(u >> 16);
        unsigned short lo = f2bf_rne(x - __uint_as_float(u & 0xffff0000u));
        if (br) { fihi[e] = hi; filo[e] = lo; }
        else    { fuhi[e] = hi; fulo[e] = lo; }
    }
}

// ---------------------------------------------------------------------------
__global__ __launch_bounds__(256) void colsum_kernel(const float* __restrict__ tw,
                                                     float* __restrict__ colsum) {
    __shared__ float part[4][ND];
    int d = threadIdx.x & 63, p = threadIdx.x >> 6;
    float s = 0.f;
    for (int t = p; t < NT; t += 4) s += tw[t * ND + d];
    part[p][d] = s;
    __syncthreads();
    if (threadIdx.x < ND)
        colsum[d] = part[0][d] + part[1][d] + part[2][d] + part[3][d];
}

// ---------------------------------------------------------------------------
// Block = 4 waves x 2 batch elements. Wave w owns row-group w of BOTH elems.
// A: pinned asm global->reg, ping-pong buf[2][NE] (full unroll -> SSA, no
//    copies of in-flight regs), counted vmcnt(4) retirement.
// B: LDS per-half (hi/lo), 2 staging points in the whole K-loop.
__global__ __launch_bounds__(256, 2) void branch_kernel(
    const int* __restrict__ user, const int* __restrict__ item,
    const float* __restrict__ user_r_topic, const float* __restrict__ item_r_topic,
    const float* __restrict__ user_embed_w, const float* __restrict__ item_embed_w,
    const float* __restrict__ user_att_w, const float* __restrict__ item_att_w,
    const unsigned short* __restrict__ bhi, const unsigned short* __restrict__ blo,
    const unsigned short* __restrict__ fuhi, const unsigned short* __restrict__ fulo,
    const unsigned short* __restrict__ fihi, const unsigned short* __restrict__ filo,
    const float* __restrict__ fc_u_b, const float* __restrict__ fc_ru_b,
    const float* __restrict__ fc_i_b, const float* __restrict__ fc_ri_b,
    const float* __restrict__ h_u_w, const float* __restrict__ h_u_b,
    const float* __restrict__ h_i_w, const float* __restrict__ h_i_b,
    const float* __restrict__ colsum,
    float* __restrict__ u_vec, float* __restrict__ i_vec)
{
    // arena: B-half hi [0,32K) + lo [32K,64K). rev[2][50][68] overlays after.
    __shared__ __align__(16) unsigned char arena[65536];
    __shared__ float lds_logit[NE][NR + 2];

    const int tid = threadIdx.x, wave = tid >> 6, lane = tid & 63;
    const int g = lane >> 4, c16 = lane & 15;

    const int E0 = blockIdx.x * NE;         // NE consecutive elems, same branch
    const int branch = E0 >> 11;            // 0 = user, 1 = item

    const int*   ids     = branch ? item           : user;
    const float* r_topic = branch ? item_r_topic   : user_r_topic;
    const float* emb_w   = branch ? item_embed_w   : user_embed_w;
    const float* att_w   = branch ? item_att_w     : user_att_w;
    const unsigned short* fhi = branch ? fihi : fuhi;
    const unsigned short* flo = branch ? filo : fulo;
    const float* fc_a_b  = branch ? fc_i_b         : fc_u_b;
    const float* fc_r_b  = branch ? fc_ri_b        : fc_ru_b;
    const float* h_w     = branch ? h_i_w          : h_u_w;
    const float* h_b     = branch ? h_i_b          : h_u_b;
    float*       out_vec = branch ? i_vec          : u_vec;

    const int rowm = wave * 16 + c16;
    const int rowc = rowm < NR ? rowm : NR - 1;

    int bidx[NE], idv[NE];
    const float* arowp[NE];
#pragma unroll
    for (int e = 0; e < NE; ++e) {
        bidx[e] = (E0 + e) & (NB - 1);
        idv[e]  = ids[bidx[e]];
        arowp[e] = r_topic + (size_t)bidx[e] * NR * NT + (size_t)rowc * NT + g * 8;
    }

    // stage one 64KB B-half (hi 32K + lo 32K) with all 256 threads
    auto stageB = [&](int h) {
        const unsigned char* srcH = (const unsigned char*)bhi + (size_t)h * 32768;
        const unsigned char* srcL = (const unsigned char*)blo + (size_t)h * 32768;
#pragma unroll
        for (int i = 0; i < 8; ++i) {
            size_t off = (size_t)(i * 256 + tid) * 16;
            gload16(srcH + off, arena + off);
            gload16(srcL + off, arena + 32768 + off);
        }
    };

    f32x4 acc[NE][4];
#pragma unroll
    for (int e = 0; e < NE; ++e)
#pragma unroll
        for (int n = 0; n < 4; ++n) acc[e][n] = (f32x4){0.f, 0.f, 0.f, 0.f};

    // ping-pong A buffers; after full unroll all indices are constants (SSA)
    float4 bufa[2][NE], bufb[2][NE];

    // ---- prologue: B half0 + pinned A loads for step 0 ----
    stageB(0);
#pragma unroll
    for (int e = 0; e < NE; ++e) {
        bufa[0][e] = gload4_pin(arowp[e]);
        bufb[0][e] = gload4_pin(arowp[e] + 4);
    }
    asm volatile("s_waitcnt vmcnt(0)" ::: "memory");
    __builtin_amdgcn_sched_barrier(0);
    __builtin_amdgcn_s_barrier();          // B half0 + A step0 ready
    __builtin_amdgcn_sched_barrier(0);

#pragma unroll
    for (int kk = 0; kk < NKK; ++kk) {
        const int cur = kk & 1, nxt = cur ^ 1;
        const int kloc = kk & 7;

        if (kk == 8) {                      // half transition (once)
            __builtin_amdgcn_sched_barrier(0);
            __builtin_amdgcn_s_barrier();   // all waves done reading half0
            __builtin_amdgcn_sched_barrier(0);
            stageB(1);                      // +16 vmem (outstanding: 4 A + 16)
        }

        // pinned issue: A for step kk+1 into buf[nxt] (no copies, fresh SSA)
        if (kk + 1 < NKK) {
#pragma unroll
            for (int e = 0; e < NE; ++e) {
                bufa[nxt][e] = gload4_pin(arowp[e] + (kk + 1) * 32);
                bufb[nxt][e] = gload4_pin(arowp[e] + (kk + 1) * 32 + 4);
            }
            // retire: everything but the newest 4 (= step kk+1's loads)
            asm volatile("s_waitcnt vmcnt(4)" ::: "memory");
        } else {
            asm volatile("s_waitcnt vmcnt(0)" ::: "memory");
        }
        __builtin_amdgcn_sched_barrier(0);

        if (kk == 8) {
            __builtin_amdgcn_s_barrier();   // B half1 visible to all waves
            __builtin_amdgcn_sched_barrier(0);
        }

        // ---- compute step kk: buf[cur] retired above ----
        bf16x8 ah[NE], al[NE];
#pragma unroll
        for (int e = 0; e < NE; ++e) cvt8_fast(bufa[cur][e], bufb[cur][e], ah[e], al[e]);
#pragma unroll
        for (int n = 0; n < 4; ++n) {
            const unsigned char* p = arena + (size_t)((kloc * 4 + n) * 64 + lane) * 16;
            bf16x8 bh = *reinterpret_cast<const bf16x8*>(p);
            bf16x8 bl = *reinterpret_cast<const bf16x8*>(p + 32768);
#pragma unroll
            for (int e = 0; e < NE; ++e) {
                acc[e][n] = __builtin_amdgcn_mfma_f32_16x16x32_bf16(ah[e], bh, acc[e][n], 0, 0, 0);
                acc[e][n] = __builtin_amdgcn_mfma_f32_16x16x32_bf16(al[e], bh, acc[e][n], 0, 0, 0);
                acc[e][n] = __builtin_amdgcn_mfma_f32_16x16x32_bf16(ah[e], bl, acc[e][n], 0, 0, 0);
            }
        }
    }

    __syncthreads();                        // all B reads done -> overlay rev
    float (*rev)[NR][REVP] = reinterpret_cast<float(*)[NR][REVP]>(arena);
#pragma unroll
    for (int e = 0; e < NE; ++e)
#pragma unroll
        for (int n = 0; n < 4; ++n)
#pragma unroll
            for (int r4 = 0; r4 < 4; ++r4) {
                int r = wave * 16 + g * 4 + r4;
                if (r < NR) rev[e][r][n * 16 + c16] = acc[e][n][r4];
            }
    // no barrier: epilogue reads only this wave's own rows

    // ---- epilogue s-matmul: s[e][50x64] = review@fcR + att@fcA (K=128) ----
    f32x4 s4[NE][4];
#pragma unroll
    for (int e = 0; e < NE; ++e)
#pragma unroll
        for (int n = 0; n < 4; ++n) s4[e][n] = (f32x4){0.f, 0.f, 0.f, 0.f};

#pragma unroll
    for (int kk2 = 0; kk2 < 4; ++kk2) {
        bf16x8 bh[4], bl[4];
#pragma unroll
        for (int n = 0; n < 4; ++n) {
            bh[n] = *(reinterpret_cast<const bf16x8*>(fhi + (size_t)(kk2 * 4 + n) * 512) + lane);
            bl[n] = *(reinterpret_cast<const bf16x8*>(flo + (size_t)(kk2 * 4 + n) * 512) + lane);
        }
#pragma unroll
        for (int e = 0; e < NE; ++e) {
            bf16x8 ah, al;
            if (kk2 < 2) {
                const float* rp = &rev[e][rowc][kk2 * 32 + g * 8];
                cvt8_fast(*reinterpret_cast<const float4*>(rp),
                          *reinterpret_cast<const float4*>(rp + 4), ah, al);
            } else {
                const float* ap = att_w + (size_t)idv[e] * ND + (kk2 - 2) * 32 + g * 8;
                cvt8_fast(*reinterpret_cast<const float4*>(ap),
                          *reinterpret_cast<const float4*>(ap + 4), ah, al);
            }
#pragma unroll
            for (int n = 0; n < 4; ++n) {
                s4[e][n] = __builtin_amdgcn_mfma_f32_16x16x32_bf16(ah, bh[n], s4[e][n], 0, 0, 0);
                s4[e][n] = __builtin_amdgcn_mfma_f32_16x16x32_bf16(al, bh[n], s4[e][n], 0, 0, 0);
                s4[e][n] = __builtin_amdgcn_mfma_f32_16x16x32_bf16(ah, bl[n], s4[e][n], 0, 0, 0);
            }
        }
    }

    // bias + relu + dot with h_w, 16-lane reduce -> logits (per element)
    const float hb = h_b[0];
#pragma unroll
    for (int e = 0; e < NE; ++e) {
        float p0 = 0.f, p1 = 0.f, p2 = 0.f, p3 = 0.f;
#pragma unroll
        for (int n = 0; n < 4; ++n) {
            float hwn = h_w[n * 16 + c16];
            float bs = fc_r_b[n * 16 + c16] + fc_a_b[n * 16 + c16];
            p0 = fmaf(fmaxf(s4[e][n][0] + bs, 0.f), hwn, p0);
            p1 = fmaf(fmaxf(s4[e][n][1] + bs, 0.f), hwn, p1);
            p2 = fmaf(fmaxf(s4[e][n][2] + bs, 0.f), hwn, p2);
            p3 = fmaf(fmaxf(s4[e][n][3] + bs, 0.f), hwn, p3);
        }
#pragma unroll
        for (int off = 1; off < 16; off <<= 1) {
            p0 += __shfl_xor(p0, off);
            p1 += __shfl_xor(p1, off);
            p2 += __shfl_xor(p2, off);
            p3 += __shfl_xor(p3, off);
        }
        if (c16 == 0) {
            int rb = wave * 16 + g * 4;
            if (rb + 0 < NR) lds_logit[e][rb + 0] = p0 + hb;
            if (rb + 1 < NR) lds_logit[e][rb + 1] = p1 + hb;
            if (rb + 2 < NR) lds_logit[e][rb + 2] = p2 + hb;
            if (rb + 3 < NR) lds_logit[e][rb + 3] = p3 + hb;
        }
    }
    __syncthreads();   // publish rev rows + logits

    // softmax + pooling + colsum scale + emb add (wave e -> elem e)
    if (wave < NE) {
        const int e = wave;
        const int b = bidx[e];
        const int id = idv[e];
        float m = -1e30f;
        for (int r = 0; r < NR; ++r) m = fmaxf(m, lds_logit[e][r]);
        float sum = 0.f;
        for (int r = 0; r < NR; ++r) sum += __expf(lds_logit[e][r] - m);
        float inv = 1.f / sum;
        float feat = 0.f;
        for (int r = 0; r < NR; ++r)
            feat = fmaf(__expf(lds_logit[e][r] - m), rev[e][r][lane], feat);
        feat *= inv;
        out_vec[(size_t)b * ND + lane] = feat * colsum[lane] + emb_w[(size_t)id * ND + lane];
    }
}

// ---------------------------------------------------------------------------
__global__ __launch_bounds__(64) void final_kernel(
    const float* __restrict__ u_vec, const float* __restrict__ i_vec,
    const float* __restrict__ fc_pre_w, const float* __restrict__ fc_pre_b,
    float* __restrict__ out)
{
    int b = blockIdx.x, lane = threadIdx.x;
    float v = u_vec[(size_t)b * ND + lane] * fc_pre_w[lane]
            + i_vec[(size_t)b * ND + lane] * fc_pre_w[ND + lane];
#pragma unroll
    for (int off = 32; off; off >>= 1) v += __shfl_xor(v, off);
    if (lane == 0) out[b] = fmaxf(v + fc_pre_b[0], 0.f);
}

// ---------------------------------------------------------------------------
extern "C" void kernel_launch(void* const* d_in, const int* in_sizes, int n_in,
                              void* d_out, int out_size, void* d_ws, size_t ws_size,
                              hipStream_t stream) {
    (void)in_sizes; (void)n_in; (void)out_size; (void)ws_size;

    const int*   user         = (const int*)d_in[0];
    const int*   item         = (const int*)d_in[1];
    const float* user_r_topic = (const float*)d_in[2];
    const float* item_r_topic = (const float*)d_in[3];
    const float* user_embed_w = (const float*)d_in[4];
    const float* item_embed_w = (const float*)d_in[5];
    const float* user_att_w   = (const float*)d_in[6];
    const float* item_att_w   = (const float*)d_in[7];
    const float* topic_w      = (const float*)d_in[8];
    const float* fc_u_w       = (const float*)d_in[9];
    const float* fc_u_b       = (const float*)d_in[10];
    const float* fc_ru_w      = (const float*)d_in[11];
    const float* fc_ru_b      = (const float*)d_in[12];
    const float* fc_i_w       = (const float*)d_in[13];
    const float* fc_i_b       = (const float*)d_in[14];
    const float* fc_ri_w      = (const float*)d_in[15];
    const float* fc_ri_b      = (const float*)d_in[16];
    const float* h_u_w        = (const float*)d_in[17];
    const float* h_u_b        = (const float*)d_in[18];
    const float* h_i_w        = (const float*)d_in[19];
    const float* h_i_b        = (const float*)d_in[20];
    const float* fc_pre_w     = (const float*)d_in[21];
    const float* fc_pre_b     = (const float*)d_in[22];

    // workspace layout
    unsigned short* bhi  = (unsigned short*)d_ws;      // 32768
    unsigned short* blo  = bhi + 32768;                // 32768
    unsigned short* fuhi = blo + 32768;                // 8192
    unsigned short* fulo = fuhi + 8192;
    unsigned short* fihi = fulo + 8192;
    unsigned short* filo = fihi + 8192;
    float* colsum = (float*)(filo + 8192);             // 64
    float* u_vec  = colsum + 64;                       // NB*ND
    float* i_vec  = u_vec + NB * ND;                   // NB*ND

    prep_kernel<<<192, 256, 0, stream>>>(topic_w, fc_u_w, fc_ru_w, fc_i_w, fc_ri_w,
                                         bhi, blo, fuhi, fulo, fihi, filo);
    colsum_kernel<<<1, 256, 0, stream>>>(topic_w, colsum);

    branch_kernel<<<(2 * NB) / NE, 256, 0, stream>>>(
        user, item, user_r_topic, item_r_topic,
        user_embed_w, item_embed_w, user_att_w, item_att_w,
        bhi, blo, fuhi, fulo, fihi, filo,
        fc_u_b, fc_ru_b, fc_i_b, fc_ri_b,
        h_u_w, h_u_b, h_i_w, h_i_b,
        colsum, u_vec, i_vec);

    final_kernel<<<NB, 64, 0, stream>>>(u_vec, i_vec, fc_pre_w, fc_pre_b,
                                        (float*)d_out);
}